// Round 16
// baseline (307.396 us; speedup 1.0000x reference)
//
#include <hip/hip_runtime.h>

using short8 = __attribute__((ext_vector_type(8))) short;
using u32x4  = __attribute__((ext_vector_type(4))) unsigned;
using u32x2  = __attribute__((ext_vector_type(2))) unsigned;
using f32x4  = __attribute__((ext_vector_type(4))) float;

#define LB 136                      // bf16 row stride (shorts) = 272 B
#define P2_OFF 8704                 // shorts
#define WA_OFF 17408                // shorts
#define SM_SHORTS 25600             // 51200 B + 2048 B sbias = 53248 -> 3 blocks/CU

#define PK_CW1 0
#define PK_CW2 16384
#define PK_DW1 32768
#define PK_DW2 49152
#define PK_FW1 65536
#define PK_FW2 98304
#define BF_OFF 262144               // byte offset of folded biases in ws

__device__ __forceinline__ short f2bf(float f) {
  __bf16 h = (__bf16)f;
  return __builtin_bit_cast(short, h);
}
__device__ __forceinline__ float bf2f(short s) {
  unsigned u = ((unsigned)(unsigned short)s) << 16;
  return __builtin_bit_cast(float, u);
}
__device__ __forceinline__ unsigned pkbf(float lo, float hi) {
  return ((unsigned)(unsigned short)f2bf(hi) << 16) | (unsigned)(unsigned short)f2bf(lo);
}
__device__ __forceinline__ float bfLo(unsigned u) {
  return __builtin_bit_cast(float, u << 16);
}
__device__ __forceinline__ float bfHi(unsigned u) {
  return __builtin_bit_cast(float, u & 0xffff0000u);
}

__device__ __forceinline__ float gelu_f(float x) {
  float x2 = x * x;
  float u2 = x * fmaf(x2, 0.1029442495f, 2.3021181583f);
  float e  = __builtin_amdgcn_exp2f(u2);
  float r  = __builtin_amdgcn_rcpf(1.0f + e);
  return fmaf(-x, r, x);
}

__device__ __forceinline__ f32x4 mfma16(short8 a, short8 b, f32x4 c) {
  return __builtin_amdgcn_mfma_f32_16x16x32_bf16(a, b, c, 0, 0, 0);
}

// async global->LDS, 16 B per lane: dest = uniform base + lane*16; src per-lane.
__device__ __forceinline__ void gload_lds16(const short* g, short* l) {
  __builtin_amdgcn_global_load_lds(
      (const __attribute__((address_space(1))) unsigned int*)g,
      (__attribute__((address_space(3))) unsigned int*)l, 16, 0, 0);
}

// Stage phase-C W1 frags of slice u: 16 frags (c:0-7, d:8-15), wave w stages 4.
__device__ __forceinline__ void stageC(const short* pk, short* buf, int u, int w, int l) {
  #pragma unroll
  for (int j = 0; j < 4; ++j) {
    int f = 4 * w + j;
    int mat = f >> 3, idx = f & 7, kk = idx >> 1, pp = idx & 1;
    const short* src = pk + (mat ? PK_DW1 : PK_CW1) + (kk * 8 + 2 * u + pp) * 512 + l * 8;
    gload_lds16(src, buf + f * 512);
  }
}
// Stage phase-E W1 frags of slices (2v, 2v+1): 16 frags, wave w stages 4.
__device__ __forceinline__ void stageE2(const short* pk, short* buf, int v, int w, int l) {
  #pragma unroll
  for (int j = 0; j < 4; ++j) {
    int f = 4 * w + j;
    int su = f >> 3, idx = f & 7, kk = idx >> 1, pp = idx & 1;
    const short* src = pk + PK_FW1 + (kk * 16 + 2 * (2 * v + su) + pp) * 512 + l * 8;
    gload_lds16(src, buf + f * 512);
  }
}

// Build layer-2 B-fragment for slice u; W1 frags from LDS (wbl = buf half + l*8).
// MFMA chains wrapped in setprio(1) (T5: favor matrix-pipe wave on CU scheduler).
__device__ __forceinline__ short8 bfrag_lds(const short* wbl,
    const float* b1, int u, int h, int src0, int src1, bool lo2,
    short8 s0, short8 s1, short8 s2, short8 s3) {
  const f32x4 Z = {0.f, 0.f, 0.f, 0.f};
  short8 wa0 = *(const short8*)&wbl[0 * 512];
  short8 wb0 = *(const short8*)&wbl[1 * 512];
  short8 wa1 = *(const short8*)&wbl[2 * 512];
  short8 wb1 = *(const short8*)&wbl[3 * 512];
  short8 wa2 = *(const short8*)&wbl[4 * 512];
  short8 wb2 = *(const short8*)&wbl[5 * 512];
  short8 wa3 = *(const short8*)&wbl[6 * 512];
  short8 wb3 = *(const short8*)&wbl[7 * 512];
  __builtin_amdgcn_s_setprio(1);
  f32x4 F0 = Z, F1 = Z;
  F0 = mfma16(wa0, s0, F0); F1 = mfma16(wb0, s0, F1);
  F0 = mfma16(wa1, s1, F0); F1 = mfma16(wb1, s1, F1);
  F0 = mfma16(wa2, s2, F0); F1 = mfma16(wb2, s2, F1);
  F0 = mfma16(wa3, s3, F0); F1 = mfma16(wb3, s3, F1);
  __builtin_amdgcn_s_setprio(0);
  float4 ba = *(const float4*)&b1[16 * (2 * u) + 4 * h];
  float4 bb = *(const float4*)&b1[16 * (2 * u + 1) + 4 * h];
  unsigned Ta0 = pkbf(gelu_f(F0[0] + ba.x), gelu_f(F0[1] + ba.y));
  unsigned Tb0 = pkbf(gelu_f(F0[2] + ba.z), gelu_f(F0[3] + ba.w));
  unsigned Ta1 = pkbf(gelu_f(F1[0] + bb.x), gelu_f(F1[1] + bb.y));
  unsigned Tb1 = pkbf(gelu_f(F1[2] + bb.z), gelu_f(F1[3] + bb.w));
  unsigned A1 = (unsigned)__shfl((int)Ta0, src0);
  unsigned A2 = (unsigned)__shfl((int)Ta1, src0);
  unsigned B1 = (unsigned)__shfl((int)Tb0, src0);
  unsigned B2 = (unsigned)__shfl((int)Tb1, src0);
  unsigned C1 = (unsigned)__shfl((int)Ta0, src1);
  unsigned C2 = (unsigned)__shfl((int)Ta1, src1);
  unsigned D1 = (unsigned)__shfl((int)Tb0, src1);
  unsigned D2 = (unsigned)__shfl((int)Tb1, src1);
  u32x4 dwf;
  dwf[0] = lo2 ? A1 : A2;
  dwf[1] = lo2 ? B1 : B2;
  dwf[2] = lo2 ? C1 : C2;
  dwf[3] = lo2 ? D1 : D2;
  return __builtin_bit_cast(short8, dwf);
}

// Fragment-major bf16 prepack; W1-type rows scaled by ln_g (g-folding).
__global__ void pack_weights_k(const float* __restrict__ cW1, const float* __restrict__ cW2,
                               const float* __restrict__ dW1, const float* __restrict__ dW2,
                               const float* __restrict__ fW1, const float* __restrict__ fW2,
                               const float* __restrict__ g, short* __restrict__ pk) {
  int fid  = blockIdx.x * 256 + threadIdx.x;
  int lane = fid & 63;
  int fbg  = fid >> 6;
  const float* W; int N; int fb; bool sc;
  if (fbg < 32)       { W = cW1; N = 128; fb = fbg;       sc = true;  }
  else if (fbg < 64)  { W = cW2; N = 128; fb = fbg - 32;  sc = false; }
  else if (fbg < 96)  { W = dW1; N = 128; fb = fbg - 64;  sc = true;  }
  else if (fbg < 128) { W = dW2; N = 128; fb = fbg - 96;  sc = false; }
  else if (fbg < 192) { W = fW1; N = 256; fb = fbg - 128; sc = true;  }
  else                { W = fW2; N = 128; fb = fbg - 192; sc = false; }
  int nt = fb % (N >> 4);
  int kk = fb / (N >> 4);
  int row0 = kk * 32 + (lane >> 4) * 8;
  int col  = nt * 16 + (lane & 15);
  short8 v;
  #pragma unroll
  for (int j = 0; j < 8; ++j) {
    float s = sc ? g[row0 + j] : 1.0f;
    v[j] = f2bf(W[(row0 + j) * N + col] * s);
  }
  *(short8*)&pk[fbg * 512 + lane * 8] = v;
}

// Folded layer-1 biases: bf[0:128)=ln_b@cW1+c_b1, [128:256)=d_b1, [256:512)=ln_b@fW1+f_b1
__global__ void bias_fold_k(const float* __restrict__ lnb,
                            const float* __restrict__ cW1, const float* __restrict__ cb1,
                            const float* __restrict__ db1,
                            const float* __restrict__ fW1, const float* __restrict__ fb1,
                            float* __restrict__ bo) {
  int tid = blockIdx.x * 256 + threadIdx.x;
  if (tid < 128) {
    float s = cb1[tid];
    for (int k = 0; k < 128; ++k) s = fmaf(lnb[k], cW1[k * 128 + tid], s);
    bo[tid] = s;
  } else if (tid < 256) {
    bo[tid] = db1[tid - 128];
  } else if (tid < 512) {
    int n = tid - 256;
    float s = fb1[n];
    for (int k = 0; k < 128; ++k) s = fmaf(lnb[k], fW1[k * 256 + n], s);
    bo[256 + n] = s;
  }
}

// Phase A: load x, row-LN stats, pair-combine via shfl_xor(16) -> P1; x -> XPv.
#define PHASE_A(i, XPv)                                                          \
  {                                                                              \
    int row = 4 * w + h + 16 * (i);                                              \
    float4 a = xg[row * 32 + 2 * c];                                             \
    float4 b = xg[row * 32 + 2 * c + 1];                                         \
    float v0 = a.x, v1 = a.y, v2 = a.z, v3 = a.w;                                \
    float v4 = b.x, v5 = b.y, v6 = b.z, v7 = b.w;                                \
    float s = v0 + v1 + v2 + v3 + v4 + v5 + v6 + v7;                             \
    float q = v0 * v0; q = fmaf(v1, v1, q); q = fmaf(v2, v2, q);                 \
    q = fmaf(v3, v3, q); q = fmaf(v4, v4, q); q = fmaf(v5, v5, q);               \
    q = fmaf(v6, v6, q); q = fmaf(v7, v7, q);                                    \
    s += __shfl_xor(s, 1); q += __shfl_xor(q, 1);                                \
    s += __shfl_xor(s, 2); q += __shfl_xor(q, 2);                                \
    s += __shfl_xor(s, 4); q += __shfl_xor(q, 4);                                \
    s += __shfl_xor(s, 8); q += __shfl_xor(q, 8);                                \
    float mu = s * (1.0f / 128.0f);                                              \
    float rs = rsqrtf(q * (1.0f / 128.0f) - mu * mu + 1e-5f);                    \
    float nb = -mu * rs;                                                         \
    int jrow = 2 * w + (h >> 1) + 8 * (i) + 32 * (h & 1);                        \
    u32x4 nv;                                                                    \
    float n0 = fmaf(v0, rs, nb), n1 = fmaf(v1, rs, nb);                          \
    float o0 = __shfl_xor(n0, 16), o1 = __shfl_xor(n1, 16);                      \
    nv[0] = pkbf(fmaf(sfac, n0, 0.5f * o0), fmaf(sfac, n1, 0.5f * o1));          \
    n0 = fmaf(v2, rs, nb); n1 = fmaf(v3, rs, nb);                                \
    o0 = __shfl_xor(n0, 16); o1 = __shfl_xor(n1, 16);                            \
    nv[1] = pkbf(fmaf(sfac, n0, 0.5f * o0), fmaf(sfac, n1, 0.5f * o1));          \
    n0 = fmaf(v4, rs, nb); n1 = fmaf(v5, rs, nb);                                \
    o0 = __shfl_xor(n0, 16); o1 = __shfl_xor(n1, 16);                            \
    nv[2] = pkbf(fmaf(sfac, n0, 0.5f * o0), fmaf(sfac, n1, 0.5f * o1));          \
    n0 = fmaf(v6, rs, nb); n1 = fmaf(v7, rs, nb);                                \
    o0 = __shfl_xor(n0, 16); o1 = __shfl_xor(n1, 16);                            \
    nv[3] = pkbf(fmaf(sfac, n0, 0.5f * o0), fmaf(sfac, n1, 0.5f * o1));          \
    *(short8*)&P1[jrow * LB + 8 * c] = __builtin_bit_cast(short8, nv);           \
    XPv[0] = pkbf(v0, v1); XPv[1] = pkbf(v2, v3);                                \
    XPv[2] = pkbf(v4, v5); XPv[3] = pkbf(v6, v7);                                \
  }

// Phase R+D: out = x + uc +- ud; LN(out); frag row -> P1; XPv := out (bf16 pairs)
#define PHASE_R(i, XPv)                                                          \
  {                                                                              \
    int j = 2 * w + (h >> 1) + 8 * (i);                                          \
    short8 uc8 = *(const short8*)&P2[j * LB + 8 * c];                            \
    short8 ud8 = *(const short8*)&P2[(32 + j) * LB + 8 * c];                     \
    float o0 = fmaf(sfac2, bf2f(ud8[0]), bfLo(XPv[0]) + bf2f(uc8[0]));           \
    float o1 = fmaf(sfac2, bf2f(ud8[1]), bfHi(XPv[0]) + bf2f(uc8[1]));           \
    float o2 = fmaf(sfac2, bf2f(ud8[2]), bfLo(XPv[1]) + bf2f(uc8[2]));           \
    float o3 = fmaf(sfac2, bf2f(ud8[3]), bfHi(XPv[1]) + bf2f(uc8[3]));           \
    float o4 = fmaf(sfac2, bf2f(ud8[4]), bfLo(XPv[2]) + bf2f(uc8[4]));           \
    float o5 = fmaf(sfac2, bf2f(ud8[5]), bfHi(XPv[2]) + bf2f(uc8[5]));           \
    float o6 = fmaf(sfac2, bf2f(ud8[6]), bfLo(XPv[3]) + bf2f(uc8[6]));           \
    float o7 = fmaf(sfac2, bf2f(ud8[7]), bfHi(XPv[3]) + bf2f(uc8[7]));           \
    float s = o0 + o1 + o2 + o3 + o4 + o5 + o6 + o7;                             \
    float q = o0 * o0; q = fmaf(o1, o1, q); q = fmaf(o2, o2, q);                 \
    q = fmaf(o3, o3, q); q = fmaf(o4, o4, q); q = fmaf(o5, o5, q);               \
    q = fmaf(o6, o6, q); q = fmaf(o7, o7, q);                                    \
    s += __shfl_xor(s, 1); q += __shfl_xor(q, 1);                                \
    s += __shfl_xor(s, 2); q += __shfl_xor(q, 2);                                \
    s += __shfl_xor(s, 4); q += __shfl_xor(q, 4);                                \
    s += __shfl_xor(s, 8); q += __shfl_xor(q, 8);                                \
    float mu = s * (1.0f / 128.0f);                                              \
    float rs = rsqrtf(q * (1.0f / 128.0f) - mu * mu + 1e-5f);                    \
    float nb = -mu * rs;                                                         \
    int row = 4 * w + h + 16 * (i);                                              \
    u32x4 nv;                                                                    \
    nv[0] = pkbf(fmaf(o0, rs, nb), fmaf(o1, rs, nb));                            \
    nv[1] = pkbf(fmaf(o2, rs, nb), fmaf(o3, rs, nb));                            \
    nv[2] = pkbf(fmaf(o4, rs, nb), fmaf(o5, rs, nb));                            \
    nv[3] = pkbf(fmaf(o6, rs, nb), fmaf(o7, rs, nb));                            \
    *(short8*)&P1[row * LB + 8 * c] = __builtin_bit_cast(short8, nv);            \
    XPv[0] = pkbf(o0, o1); XPv[1] = pkbf(o2, o3);                                \
    XPv[2] = pkbf(o4, o5); XPv[3] = pkbf(o6, o7);                                \
  }

// Final: out = out_reg + upd, coalesced float4 store
#define STORE_F(i, XPv)                                                          \
  {                                                                              \
    int row = 4 * w + h + 16 * (i);                                              \
    short8 u8 = *(const short8*)&P2[row * LB + 8 * c];                           \
    float4 a, b;                                                                 \
    a.x = bfLo(XPv[0]) + bf2f(u8[0]); a.y = bfHi(XPv[0]) + bf2f(u8[1]);          \
    a.z = bfLo(XPv[1]) + bf2f(u8[2]); a.w = bfHi(XPv[1]) + bf2f(u8[3]);          \
    b.x = bfLo(XPv[2]) + bf2f(u8[4]); b.y = bfHi(XPv[2]) + bf2f(u8[5]);          \
    b.z = bfLo(XPv[3]) + bf2f(u8[6]); b.w = bfHi(XPv[3]) + bf2f(u8[7]);          \
    og[row * 32 + 2 * c]     = a;                                                \
    og[row * 32 + 2 * c + 1] = b;                                                \
  }

__global__ __launch_bounds__(256, 3)
void hemi_fused_k(const float* __restrict__ x, const short* __restrict__ pk,
                  const float* __restrict__ bf1,
                  const float* __restrict__ c_b2, const float* __restrict__ d_b2,
                  const float* __restrict__ f_b2,
                  float* __restrict__ out) {
  __shared__ short sm[SM_SHORTS];
  __shared__ float sbias[512];     // layer-1 folded biases (critical path)
  short* P1 = sm;                  // act frag rows
  short* P2 = sm + P2_OFF;         // uc/ud + upd; doubles as W1 staging buf B
  short* WA = sm + WA_OFF;         // W1 staging buf A (16 KB)

  const int t = threadIdx.x;
  const int w = t >> 6, l = t & 63;
  const int h = l >> 4, c = l & 15;
  const size_t base = (size_t)blockIdx.x * 8192;

  stageC(pk, WA, 0, w, l);         // C slice-0 W1 in flight under phase A
  #pragma unroll
  for (int i = t; i < 512; i += 256) sbias[i] = bf1[i];

  const float4* xg = (const float4*)(x + base);
  const float sfac  = (h & 1) ? -0.5f : 0.5f;
  const float sfac2 = (h & 1) ? -1.0f : 1.0f;

  u32x4 xp0, xp1, xp2, xp3;        // x (later out) as packed bf16 pairs

  PHASE_A(0, xp0)
  PHASE_A(1, xp1)
  PHASE_A(2, xp2)
  PHASE_A(3, xp3)
  __syncthreads();   // sync1: cmn/dif + biases + C-slice0 W1 ready

  const int src0 = c + 32 * (h & 1);
  const int src1 = src0 + 16;
  const bool lo2 = (h < 2);
  const f32x4 Z = {0.f, 0.f, 0.f, 0.f};

  // ---------------- Phase C: pair-MLP; W1 double-buffered WA <-> P2
  {
    const short* W2    = pk + ((w < 2) ? PK_CW2 : PK_DW2) + l * 8;
    const float* bias1 = sbias + ((w < 2) ? 0 : 128);
    const int arow = 16 * (w & 1) + 32 * (w >> 1);
    const short* wbl = ((w < 2) ? WA : WA + 4096) + l * 8;
    const short* pbl = ((w < 2) ? P2 : P2 + 4096) + l * 8;
    short8 s0 = *(const short8*)&P1[(arow + c) * LB +  0 + 8 * h];
    short8 s1 = *(const short8*)&P1[(arow + c) * LB + 32 + 8 * h];
    short8 s2 = *(const short8*)&P1[(arow + c) * LB + 64 + 8 * h];
    short8 s3 = *(const short8*)&P1[(arow + c) * LB + 96 + 8 * h];
    f32x4 A0 = Z, A1 = Z, A2 = Z, A3 = Z, A4 = Z, A5 = Z, A6 = Z, A7 = Z;
#define C_SLICE(u, RDP)                                                   \
    {                                                                     \
      short8 G = bfrag_lds(RDP, bias1, (u), h, src0, src1, lo2,           \
                           s0, s1, s2, s3);                               \
      __builtin_amdgcn_s_setprio(1);                                      \
      A0 = mfma16(*(const short8*)&W2[((u) * 8 + 0) * 512], G, A0);       \
      A1 = mfma16(*(const short8*)&W2[((u) * 8 + 1) * 512], G, A1);       \
      A2 = mfma16(*(const short8*)&W2[((u) * 8 + 2) * 512], G, A2);       \
      A3 = mfma16(*(const short8*)&W2[((u) * 8 + 3) * 512], G, A3);       \
      A4 = mfma16(*(const short8*)&W2[((u) * 8 + 4) * 512], G, A4);       \
      A5 = mfma16(*(const short8*)&W2[((u) * 8 + 5) * 512], G, A5);       \
      A6 = mfma16(*(const short8*)&W2[((u) * 8 + 6) * 512], G, A6);       \
      A7 = mfma16(*(const short8*)&W2[((u) * 8 + 7) * 512], G, A7);       \
      __builtin_amdgcn_s_setprio(0);                                      \
    }
    stageC(pk, P2, 1, w, l);  C_SLICE(0, wbl)  __syncthreads();
    stageC(pk, WA, 2, w, l);  C_SLICE(1, pbl)  __syncthreads();
    stageC(pk, P2, 3, w, l);  C_SLICE(2, wbl)  __syncthreads();
                              C_SLICE(3, pbl)  __syncthreads();  // syncC
#undef C_SLICE
    const float* bias2 = (w < 2) ? c_b2 : d_b2;
#define C_EPI(t2, A)                                                      \
    {                                                                     \
      float4 b4 = *(const float4*)&bias2[16 * (t2) + 4 * h];              \
      u32x2 dd;                                                           \
      dd[0] = pkbf(A[0] + b4.x, A[1] + b4.y);                             \
      dd[1] = pkbf(A[2] + b4.z, A[3] + b4.w);                             \
      *(u32x2*)&P2[(arow + c) * LB + 16 * (t2) + 4 * h] = dd;             \
    }
    C_EPI(0, A0) C_EPI(1, A1) C_EPI(2, A2) C_EPI(3, A3)
    C_EPI(4, A4) C_EPI(5, A5) C_EPI(6, A6) C_EPI(7, A7)
#undef C_EPI
  }
  __syncthreads();   // sync2: uc/ud complete

  stageE2(pk, WA, 0, w, l);   // E slices 0,1 W1 in flight under phase R
  PHASE_R(0, xp0)
  PHASE_R(1, xp1)
  PHASE_R(2, xp2)
  PHASE_R(3, xp3)
  __syncthreads();   // sync3: n_out + E slices 0,1 ready; P2 uc/ud consumed

  // ---------------- Phase E: f-MLP; W1 2-slice staged, dbuf WA <-> P2 (4 barriers)
  {
    const short* W2    = pk + PK_FW2 + l * 8;
    const float* biasF = sbias + 256;
    const short* wbl0 = WA + l * 8;
    const short* wbl1 = WA + 4096 + l * 8;
    const short* pbl0 = P2 + l * 8;
    const short* pbl1 = P2 + 4096 + l * 8;
    const int nrow = (16 * w + c) * LB + 8 * h;
    short8 n0 = *(const short8*)&P1[nrow +  0];
    short8 n1 = *(const short8*)&P1[nrow + 32];
    short8 n2 = *(const short8*)&P1[nrow + 64];
    short8 n3 = *(const short8*)&P1[nrow + 96];
    f32x4 A0 = Z, A1 = Z, A2 = Z, A3 = Z, A4 = Z, A5 = Z, A6 = Z, A7 = Z;
#define E_SLICE(u, RDP)                                                   \
    {                                                                     \
      short8 G = bfrag_lds(RDP, biasF, (u), h, src0, src1, lo2,           \
                           n0, n1, n2, n3);                               \
      __builtin_amdgcn_s_setprio(1);                                      \
      A0 = mfma16(*(const short8*)&W2[((u) * 8 + 0) * 512], G, A0);       \
      A1 = mfma16(*(const short8*)&W2[((u) * 8 + 1) * 512], G, A1);       \
      A2 = mfma16(*(const short8*)&W2[((u) * 8 + 2) * 512], G, A2);       \
      A3 = mfma16(*(const short8*)&W2[((u) * 8 + 3) * 512], G, A3);       \
      A4 = mfma16(*(const short8*)&W2[((u) * 8 + 4) * 512], G, A4);       \
      A5 = mfma16(*(const short8*)&W2[((u) * 8 + 5) * 512], G, A5);       \
      A6 = mfma16(*(const short8*)&W2[((u) * 8 + 6) * 512], G, A6);       \
      A7 = mfma16(*(const short8*)&W2[((u) * 8 + 7) * 512], G, A7);       \
      __builtin_amdgcn_s_setprio(0);                                      \
    }
    stageE2(pk, P2, 1, w, l);                       // slices 2,3 -> P2
    E_SLICE(0, wbl0)
    E_SLICE(1, wbl1)
    __syncthreads();
    stageE2(pk, WA, 2, w, l);                       // slices 4,5 -> WA
    E_SLICE(2, pbl0)
    E_SLICE(3, pbl1)
    __syncthreads();
    stageE2(pk, P2, 3, w, l);                       // slices 6,7 -> P2
    E_SLICE(4, wbl0)
    E_SLICE(5, wbl1)
    __syncthreads();
    E_SLICE(6, pbl0)
    E_SLICE(7, pbl1)
    __syncthreads();   // syncE: all P2-staged reads done
#undef E_SLICE
#define E_EPI(t2, A)                                                      \
    {                                                                     \
      float4 b4 = *(const float4*)&f_b2[16 * (t2) + 4 * h];               \
      u32x2 dd;                                                           \
      dd[0] = pkbf(A[0] + b4.x, A[1] + b4.y);                             \
      dd[1] = pkbf(A[2] + b4.z, A[3] + b4.w);                             \
      *(u32x2*)&P2[(16 * w + c) * LB + 16 * (t2) + 4 * h] = dd;           \
    }
    E_EPI(0, A0) E_EPI(1, A1) E_EPI(2, A2) E_EPI(3, A3)
    E_EPI(4, A4) E_EPI(5, A5) E_EPI(6, A6) E_EPI(7, A7)
#undef E_EPI
  }
  __syncthreads();   // sync4: upd complete

  float4* og = (float4*)(out + base);
  STORE_F(0, xp0)
  STORE_F(1, xp1)
  STORE_F(2, xp2)
  STORE_F(3, xp3)
}

extern "C" void kernel_launch(void* const* d_in, const int* in_sizes, int n_in,
                              void* d_out, int out_size, void* d_ws, size_t ws_size,
                              hipStream_t stream) {
  (void)in_sizes; (void)n_in; (void)out_size; (void)ws_size;
  const float* x    = (const float*)d_in[0];
  const float* ln_g = (const float*)d_in[1];
  const float* ln_b = (const float*)d_in[2];
  const float* cW1  = (const float*)d_in[3];
  const float* c_b1 = (const float*)d_in[4];
  const float* cW2  = (const float*)d_in[5];
  const float* c_b2 = (const float*)d_in[6];
  const float* dW1  = (const float*)d_in[7];
  const float* d_b1 = (const float*)d_in[8];
  const float* dW2  = (const float*)d_in[9];
  const float* d_b2 = (const float*)d_in[10];
  const float* fW1  = (const float*)d_in[11];
  const float* f_b1 = (const float*)d_in[12];
  const float* fW2  = (const float*)d_in[13];
  const float* f_b2 = (const float*)d_in[14];
  short* pk   = (short*)d_ws;                         // 256 KB fragments
  float* bfv  = (float*)((char*)d_ws + BF_OFF);       // 512 folded-bias floats
  float* out  = (float*)d_out;

  pack_weights_k<<<64, 256, 0, stream>>>(cW1, cW2, dW1, dW2, fW1, fW2, ln_g, pk);
  bias_fold_k<<<2, 256, 0, stream>>>(ln_b, cW1, c_b1, d_b1, fW1, f_b1, bfv);
  hemi_fused_k<<<8192, 256, 0, stream>>>(x, pk, bfv, c_b2, d_b2, f_b2, out);
}

// Round 17
// 284.498 us; speedup vs baseline: 1.0805x; 1.0805x over previous
//
#include <hip/hip_runtime.h>

using short8 = __attribute__((ext_vector_type(8))) short;
using u32x4  = __attribute__((ext_vector_type(4))) unsigned;
using u32x2  = __attribute__((ext_vector_type(2))) unsigned;
using f32x4  = __attribute__((ext_vector_type(4))) float;

#define LB 136                      // bf16 row stride (shorts) = 272 B
#define P2_OFF 8704                 // shorts
#define WA_OFF 17408                // shorts
#define SM_SHORTS 25600             // 51200 B + 2048 B sbias = 53248 -> 3 blocks/CU

#define PK_CW1 0
#define PK_CW2 16384
#define PK_DW1 32768
#define PK_DW2 49152
#define PK_FW1 65536
#define PK_FW2 98304
#define BF_OFF 262144               // byte offset of folded biases in ws

__device__ __forceinline__ short f2bf(float f) {
  __bf16 h = (__bf16)f;
  return __builtin_bit_cast(short, h);
}
__device__ __forceinline__ float bf2f(short s) {
  unsigned u = ((unsigned)(unsigned short)s) << 16;
  return __builtin_bit_cast(float, u);
}
__device__ __forceinline__ unsigned pkbf(float lo, float hi) {
  return ((unsigned)(unsigned short)f2bf(hi) << 16) | (unsigned)(unsigned short)f2bf(lo);
}
__device__ __forceinline__ float bfLo(unsigned u) {
  return __builtin_bit_cast(float, u << 16);
}
__device__ __forceinline__ float bfHi(unsigned u) {
  return __builtin_bit_cast(float, u & 0xffff0000u);
}

__device__ __forceinline__ float gelu_f(float x) {
  float x2 = x * x;
  float u2 = x * fmaf(x2, 0.1029442495f, 2.3021181583f);
  float e  = __builtin_amdgcn_exp2f(u2);
  float r  = __builtin_amdgcn_rcpf(1.0f + e);
  return fmaf(-x, r, x);
}

__device__ __forceinline__ f32x4 mfma16(short8 a, short8 b, f32x4 c) {
  return __builtin_amdgcn_mfma_f32_16x16x32_bf16(a, b, c, 0, 0, 0);
}

// async global->LDS, 16 B per lane: dest = uniform base + lane*16; src per-lane.
__device__ __forceinline__ void gload_lds16(const short* g, short* l) {
  __builtin_amdgcn_global_load_lds(
      (const __attribute__((address_space(1))) unsigned int*)g,
      (__attribute__((address_space(3))) unsigned int*)l, 16, 0, 0);
}

// Stage phase-C W1 frags of slice u: 16 frags (c:0-7, d:8-15), wave w stages 4.
__device__ __forceinline__ void stageC(const short* pk, short* buf, int u, int w, int l) {
  #pragma unroll
  for (int j = 0; j < 4; ++j) {
    int f = 4 * w + j;
    int mat = f >> 3, idx = f & 7, kk = idx >> 1, pp = idx & 1;
    const short* src = pk + (mat ? PK_DW1 : PK_CW1) + (kk * 8 + 2 * u + pp) * 512 + l * 8;
    gload_lds16(src, buf + f * 512);
  }
}
// Stage phase-E W1 frags of slices (2v, 2v+1): 16 frags, wave w stages 4.
__device__ __forceinline__ void stageE2(const short* pk, short* buf, int v, int w, int l) {
  #pragma unroll
  for (int j = 0; j < 4; ++j) {
    int f = 4 * w + j;
    int su = f >> 3, idx = f & 7, kk = idx >> 1, pp = idx & 1;
    const short* src = pk + PK_FW1 + (kk * 16 + 2 * (2 * v + su) + pp) * 512 + l * 8;
    gload_lds16(src, buf + f * 512);
  }
}

// Build layer-2 B-fragment for slice u; W1 frags from LDS (wbl = buf half + l*8).
__device__ __forceinline__ short8 bfrag_lds(const short* wbl,
    const float* b1, int u, int h, int src0, int src1, bool lo2,
    short8 s0, short8 s1, short8 s2, short8 s3) {
  const f32x4 Z = {0.f, 0.f, 0.f, 0.f};
  short8 wa0 = *(const short8*)&wbl[0 * 512];
  short8 wb0 = *(const short8*)&wbl[1 * 512];
  short8 wa1 = *(const short8*)&wbl[2 * 512];
  short8 wb1 = *(const short8*)&wbl[3 * 512];
  short8 wa2 = *(const short8*)&wbl[4 * 512];
  short8 wb2 = *(const short8*)&wbl[5 * 512];
  short8 wa3 = *(const short8*)&wbl[6 * 512];
  short8 wb3 = *(const short8*)&wbl[7 * 512];
  f32x4 F0 = Z, F1 = Z;
  F0 = mfma16(wa0, s0, F0); F1 = mfma16(wb0, s0, F1);
  F0 = mfma16(wa1, s1, F0); F1 = mfma16(wb1, s1, F1);
  F0 = mfma16(wa2, s2, F0); F1 = mfma16(wb2, s2, F1);
  F0 = mfma16(wa3, s3, F0); F1 = mfma16(wb3, s3, F1);
  float4 ba = *(const float4*)&b1[16 * (2 * u) + 4 * h];
  float4 bb = *(const float4*)&b1[16 * (2 * u + 1) + 4 * h];
  unsigned Ta0 = pkbf(gelu_f(F0[0] + ba.x), gelu_f(F0[1] + ba.y));
  unsigned Tb0 = pkbf(gelu_f(F0[2] + ba.z), gelu_f(F0[3] + ba.w));
  unsigned Ta1 = pkbf(gelu_f(F1[0] + bb.x), gelu_f(F1[1] + bb.y));
  unsigned Tb1 = pkbf(gelu_f(F1[2] + bb.z), gelu_f(F1[3] + bb.w));
  unsigned A1 = (unsigned)__shfl((int)Ta0, src0);
  unsigned A2 = (unsigned)__shfl((int)Ta1, src0);
  unsigned B1 = (unsigned)__shfl((int)Tb0, src0);
  unsigned B2 = (unsigned)__shfl((int)Tb1, src0);
  unsigned C1 = (unsigned)__shfl((int)Ta0, src1);
  unsigned C2 = (unsigned)__shfl((int)Ta1, src1);
  unsigned D1 = (unsigned)__shfl((int)Tb0, src1);
  unsigned D2 = (unsigned)__shfl((int)Tb1, src1);
  u32x4 dwf;
  dwf[0] = lo2 ? A1 : A2;
  dwf[1] = lo2 ? B1 : B2;
  dwf[2] = lo2 ? C1 : C2;
  dwf[3] = lo2 ? D1 : D2;
  return __builtin_bit_cast(short8, dwf);
}

// Fragment-major bf16 prepack; W1-type rows scaled by ln_g (g-folding).
__global__ void pack_weights_k(const float* __restrict__ cW1, const float* __restrict__ cW2,
                               const float* __restrict__ dW1, const float* __restrict__ dW2,
                               const float* __restrict__ fW1, const float* __restrict__ fW2,
                               const float* __restrict__ g, short* __restrict__ pk) {
  int fid  = blockIdx.x * 256 + threadIdx.x;
  int lane = fid & 63;
  int fbg  = fid >> 6;
  const float* W; int N; int fb; bool sc;
  if (fbg < 32)       { W = cW1; N = 128; fb = fbg;       sc = true;  }
  else if (fbg < 64)  { W = cW2; N = 128; fb = fbg - 32;  sc = false; }
  else if (fbg < 96)  { W = dW1; N = 128; fb = fbg - 64;  sc = true;  }
  else if (fbg < 128) { W = dW2; N = 128; fb = fbg - 96;  sc = false; }
  else if (fbg < 192) { W = fW1; N = 256; fb = fbg - 128; sc = true;  }
  else                { W = fW2; N = 128; fb = fbg - 192; sc = false; }
  int nt = fb % (N >> 4);
  int kk = fb / (N >> 4);
  int row0 = kk * 32 + (lane >> 4) * 8;
  int col  = nt * 16 + (lane & 15);
  short8 v;
  #pragma unroll
  for (int j = 0; j < 8; ++j) {
    float s = sc ? g[row0 + j] : 1.0f;
    v[j] = f2bf(W[(row0 + j) * N + col] * s);
  }
  *(short8*)&pk[fbg * 512 + lane * 8] = v;
}

// Folded layer-1 biases: bf[0:128)=ln_b@cW1+c_b1, [128:256)=d_b1, [256:512)=ln_b@fW1+f_b1
__global__ void bias_fold_k(const float* __restrict__ lnb,
                            const float* __restrict__ cW1, const float* __restrict__ cb1,
                            const float* __restrict__ db1,
                            const float* __restrict__ fW1, const float* __restrict__ fb1,
                            float* __restrict__ bo) {
  int tid = blockIdx.x * 256 + threadIdx.x;
  if (tid < 128) {
    float s = cb1[tid];
    for (int k = 0; k < 128; ++k) s = fmaf(lnb[k], cW1[k * 128 + tid], s);
    bo[tid] = s;
  } else if (tid < 256) {
    bo[tid] = db1[tid - 128];
  } else if (tid < 512) {
    int n = tid - 256;
    float s = fb1[n];
    for (int k = 0; k < 128; ++k) s = fmaf(lnb[k], fW1[k * 256 + n], s);
    bo[256 + n] = s;
  }
}

// Phase A: load x, row-LN stats, pair-combine via shfl_xor(16) -> P1; x -> XPv.
#define PHASE_A(i, XPv)                                                          \
  {                                                                              \
    int row = 4 * w + h + 16 * (i);                                              \
    float4 a = xg[row * 32 + 2 * c];                                             \
    float4 b = xg[row * 32 + 2 * c + 1];                                         \
    float v0 = a.x, v1 = a.y, v2 = a.z, v3 = a.w;                                \
    float v4 = b.x, v5 = b.y, v6 = b.z, v7 = b.w;                                \
    float s = v0 + v1 + v2 + v3 + v4 + v5 + v6 + v7;                             \
    float q = v0 * v0; q = fmaf(v1, v1, q); q = fmaf(v2, v2, q);                 \
    q = fmaf(v3, v3, q); q = fmaf(v4, v4, q); q = fmaf(v5, v5, q);               \
    q = fmaf(v6, v6, q); q = fmaf(v7, v7, q);                                    \
    s += __shfl_xor(s, 1); q += __shfl_xor(q, 1);                                \
    s += __shfl_xor(s, 2); q += __shfl_xor(q, 2);                                \
    s += __shfl_xor(s, 4); q += __shfl_xor(q, 4);                                \
    s += __shfl_xor(s, 8); q += __shfl_xor(q, 8);                                \
    float mu = s * (1.0f / 128.0f);                                              \
    float rs = rsqrtf(q * (1.0f / 128.0f) - mu * mu + 1e-5f);                    \
    float nb = -mu * rs;                                                         \
    int jrow = 2 * w + (h >> 1) + 8 * (i) + 32 * (h & 1);                        \
    u32x4 nv;                                                                    \
    float n0 = fmaf(v0, rs, nb), n1 = fmaf(v1, rs, nb);                          \
    float o0 = __shfl_xor(n0, 16), o1 = __shfl_xor(n1, 16);                      \
    nv[0] = pkbf(fmaf(sfac, n0, 0.5f * o0), fmaf(sfac, n1, 0.5f * o1));          \
    n0 = fmaf(v2, rs, nb); n1 = fmaf(v3, rs, nb);                                \
    o0 = __shfl_xor(n0, 16); o1 = __shfl_xor(n1, 16);                            \
    nv[1] = pkbf(fmaf(sfac, n0, 0.5f * o0), fmaf(sfac, n1, 0.5f * o1));          \
    n0 = fmaf(v4, rs, nb); n1 = fmaf(v5, rs, nb);                                \
    o0 = __shfl_xor(n0, 16); o1 = __shfl_xor(n1, 16);                            \
    nv[2] = pkbf(fmaf(sfac, n0, 0.5f * o0), fmaf(sfac, n1, 0.5f * o1));          \
    n0 = fmaf(v6, rs, nb); n1 = fmaf(v7, rs, nb);                                \
    o0 = __shfl_xor(n0, 16); o1 = __shfl_xor(n1, 16);                            \
    nv[3] = pkbf(fmaf(sfac, n0, 0.5f * o0), fmaf(sfac, n1, 0.5f * o1));          \
    *(short8*)&P1[jrow * LB + 8 * c] = __builtin_bit_cast(short8, nv);           \
    XPv[0] = pkbf(v0, v1); XPv[1] = pkbf(v2, v3);                                \
    XPv[2] = pkbf(v4, v5); XPv[3] = pkbf(v6, v7);                                \
  }

// Phase R+D: out = x + uc +- ud; LN(out); frag row -> P1; XPv := out (bf16 pairs)
#define PHASE_R(i, XPv)                                                          \
  {                                                                              \
    int j = 2 * w + (h >> 1) + 8 * (i);                                          \
    short8 uc8 = *(const short8*)&P2[j * LB + 8 * c];                            \
    short8 ud8 = *(const short8*)&P2[(32 + j) * LB + 8 * c];                     \
    float o0 = fmaf(sfac2, bf2f(ud8[0]), bfLo(XPv[0]) + bf2f(uc8[0]));           \
    float o1 = fmaf(sfac2, bf2f(ud8[1]), bfHi(XPv[0]) + bf2f(uc8[1]));           \
    float o2 = fmaf(sfac2, bf2f(ud8[2]), bfLo(XPv[1]) + bf2f(uc8[2]));           \
    float o3 = fmaf(sfac2, bf2f(ud8[3]), bfHi(XPv[1]) + bf2f(uc8[3]));           \
    float o4 = fmaf(sfac2, bf2f(ud8[4]), bfLo(XPv[2]) + bf2f(uc8[4]));           \
    float o5 = fmaf(sfac2, bf2f(ud8[5]), bfHi(XPv[2]) + bf2f(uc8[5]));           \
    float o6 = fmaf(sfac2, bf2f(ud8[6]), bfLo(XPv[3]) + bf2f(uc8[6]));           \
    float o7 = fmaf(sfac2, bf2f(ud8[7]), bfHi(XPv[3]) + bf2f(uc8[7]));           \
    float s = o0 + o1 + o2 + o3 + o4 + o5 + o6 + o7;                             \
    float q = o0 * o0; q = fmaf(o1, o1, q); q = fmaf(o2, o2, q);                 \
    q = fmaf(o3, o3, q); q = fmaf(o4, o4, q); q = fmaf(o5, o5, q);               \
    q = fmaf(o6, o6, q); q = fmaf(o7, o7, q);                                    \
    s += __shfl_xor(s, 1); q += __shfl_xor(q, 1);                                \
    s += __shfl_xor(s, 2); q += __shfl_xor(q, 2);                                \
    s += __shfl_xor(s, 4); q += __shfl_xor(q, 4);                                \
    s += __shfl_xor(s, 8); q += __shfl_xor(q, 8);                                \
    float mu = s * (1.0f / 128.0f);                                              \
    float rs = rsqrtf(q * (1.0f / 128.0f) - mu * mu + 1e-5f);                    \
    float nb = -mu * rs;                                                         \
    int row = 4 * w + h + 16 * (i);                                              \
    u32x4 nv;                                                                    \
    nv[0] = pkbf(fmaf(o0, rs, nb), fmaf(o1, rs, nb));                            \
    nv[1] = pkbf(fmaf(o2, rs, nb), fmaf(o3, rs, nb));                            \
    nv[2] = pkbf(fmaf(o4, rs, nb), fmaf(o5, rs, nb));                            \
    nv[3] = pkbf(fmaf(o6, rs, nb), fmaf(o7, rs, nb));                            \
    *(short8*)&P1[row * LB + 8 * c] = __builtin_bit_cast(short8, nv);            \
    XPv[0] = pkbf(o0, o1); XPv[1] = pkbf(o2, o3);                                \
    XPv[2] = pkbf(o4, o5); XPv[3] = pkbf(o6, o7);                                \
  }

// Final: out = out_reg + upd, coalesced float4 store
#define STORE_F(i, XPv)                                                          \
  {                                                                              \
    int row = 4 * w + h + 16 * (i);                                              \
    short8 u8 = *(const short8*)&P2[row * LB + 8 * c];                           \
    float4 a, b;                                                                 \
    a.x = bfLo(XPv[0]) + bf2f(u8[0]); a.y = bfHi(XPv[0]) + bf2f(u8[1]);          \
    a.z = bfLo(XPv[1]) + bf2f(u8[2]); a.w = bfHi(XPv[1]) + bf2f(u8[3]);          \
    b.x = bfLo(XPv[2]) + bf2f(u8[4]); b.y = bfHi(XPv[2]) + bf2f(u8[5]);          \
    b.z = bfLo(XPv[3]) + bf2f(u8[6]); b.w = bfHi(XPv[3]) + bf2f(u8[7]);          \
    og[row * 32 + 2 * c]     = a;                                                \
    og[row * 32 + 2 * c + 1] = b;                                                \
  }

__global__ __launch_bounds__(256, 3)
void hemi_fused_k(const float* __restrict__ x, const short* __restrict__ pk,
                  const float* __restrict__ bf1,
                  const float* __restrict__ c_b2, const float* __restrict__ d_b2,
                  const float* __restrict__ f_b2,
                  float* __restrict__ out) {
  __shared__ short sm[SM_SHORTS];
  __shared__ float sbias[512];     // layer-1 folded biases (critical path)
  short* P1 = sm;                  // act frag rows
  short* P2 = sm + P2_OFF;         // uc/ud + upd; doubles as W1 staging buf B
  short* WA = sm + WA_OFF;         // W1 staging buf A (16 KB)

  const int t = threadIdx.x;
  const int w = t >> 6, l = t & 63;
  const int h = l >> 4, c = l & 15;
  const size_t base = (size_t)blockIdx.x * 8192;

  stageC(pk, WA, 0, w, l);         // C slice-0 W1 in flight under phase A
  #pragma unroll
  for (int i = t; i < 512; i += 256) sbias[i] = bf1[i];

  const float4* xg = (const float4*)(x + base);
  const float sfac  = (h & 1) ? -0.5f : 0.5f;
  const float sfac2 = (h & 1) ? -1.0f : 1.0f;

  u32x4 xp0, xp1, xp2, xp3;        // x (later out) as packed bf16 pairs

  PHASE_A(0, xp0)
  PHASE_A(1, xp1)
  PHASE_A(2, xp2)
  PHASE_A(3, xp3)
  __syncthreads();   // sync1: cmn/dif + biases + C-slice0 W1 ready

  const int src0 = c + 32 * (h & 1);
  const int src1 = src0 + 16;
  const bool lo2 = (h < 2);
  const f32x4 Z = {0.f, 0.f, 0.f, 0.f};

  // ---------------- Phase C: pair-MLP; W1 double-buffered WA <-> P2
  {
    const short* W2    = pk + ((w < 2) ? PK_CW2 : PK_DW2) + l * 8;
    const float* bias1 = sbias + ((w < 2) ? 0 : 128);
    const int arow = 16 * (w & 1) + 32 * (w >> 1);
    const short* wbl = ((w < 2) ? WA : WA + 4096) + l * 8;
    const short* pbl = ((w < 2) ? P2 : P2 + 4096) + l * 8;
    short8 s0 = *(const short8*)&P1[(arow + c) * LB +  0 + 8 * h];
    short8 s1 = *(const short8*)&P1[(arow + c) * LB + 32 + 8 * h];
    short8 s2 = *(const short8*)&P1[(arow + c) * LB + 64 + 8 * h];
    short8 s3 = *(const short8*)&P1[(arow + c) * LB + 96 + 8 * h];
    f32x4 A0 = Z, A1 = Z, A2 = Z, A3 = Z, A4 = Z, A5 = Z, A6 = Z, A7 = Z;
#define C_SLICE(u, RDP)                                                   \
    {                                                                     \
      short8 G = bfrag_lds(RDP, bias1, (u), h, src0, src1, lo2,           \
                           s0, s1, s2, s3);                               \
      A0 = mfma16(*(const short8*)&W2[((u) * 8 + 0) * 512], G, A0);       \
      A1 = mfma16(*(const short8*)&W2[((u) * 8 + 1) * 512], G, A1);       \
      A2 = mfma16(*(const short8*)&W2[((u) * 8 + 2) * 512], G, A2);       \
      A3 = mfma16(*(const short8*)&W2[((u) * 8 + 3) * 512], G, A3);       \
      A4 = mfma16(*(const short8*)&W2[((u) * 8 + 4) * 512], G, A4);       \
      A5 = mfma16(*(const short8*)&W2[((u) * 8 + 5) * 512], G, A5);       \
      A6 = mfma16(*(const short8*)&W2[((u) * 8 + 6) * 512], G, A6);       \
      A7 = mfma16(*(const short8*)&W2[((u) * 8 + 7) * 512], G, A7);       \
    }
    stageC(pk, P2, 1, w, l);  C_SLICE(0, wbl)  __syncthreads();
    stageC(pk, WA, 2, w, l);  C_SLICE(1, pbl)  __syncthreads();
    stageC(pk, P2, 3, w, l);  C_SLICE(2, wbl)  __syncthreads();
                              C_SLICE(3, pbl)  __syncthreads();  // syncC
#undef C_SLICE
    const float* bias2 = (w < 2) ? c_b2 : d_b2;
#define C_EPI(t2, A)                                                      \
    {                                                                     \
      float4 b4 = *(const float4*)&bias2[16 * (t2) + 4 * h];              \
      u32x2 dd;                                                           \
      dd[0] = pkbf(A[0] + b4.x, A[1] + b4.y);                             \
      dd[1] = pkbf(A[2] + b4.z, A[3] + b4.w);                             \
      *(u32x2*)&P2[(arow + c) * LB + 16 * (t2) + 4 * h] = dd;             \
    }
    C_EPI(0, A0) C_EPI(1, A1) C_EPI(2, A2) C_EPI(3, A3)
    C_EPI(4, A4) C_EPI(5, A5) C_EPI(6, A6) C_EPI(7, A7)
#undef C_EPI
  }
  __syncthreads();   // sync2: uc/ud complete

  stageE2(pk, WA, 0, w, l);   // E slices 0,1 W1 in flight under phase R
  PHASE_R(0, xp0)
  PHASE_R(1, xp1)
  PHASE_R(2, xp2)
  PHASE_R(3, xp3)
  __syncthreads();   // sync3: n_out + E slices 0,1 ready; P2 uc/ud consumed

  // ---------------- Phase E: f-MLP; W1 2-slice staged, dbuf WA <-> P2 (4 barriers)
  {
    const short* W2    = pk + PK_FW2 + l * 8;
    const float* biasF = sbias + 256;
    const short* wbl0 = WA + l * 8;
    const short* wbl1 = WA + 4096 + l * 8;
    const short* pbl0 = P2 + l * 8;
    const short* pbl1 = P2 + 4096 + l * 8;
    const int nrow = (16 * w + c) * LB + 8 * h;
    short8 n0 = *(const short8*)&P1[nrow +  0];
    short8 n1 = *(const short8*)&P1[nrow + 32];
    short8 n2 = *(const short8*)&P1[nrow + 64];
    short8 n3 = *(const short8*)&P1[nrow + 96];
    f32x4 A0 = Z, A1 = Z, A2 = Z, A3 = Z, A4 = Z, A5 = Z, A6 = Z, A7 = Z;
#define E_SLICE(u, RDP)                                                   \
    {                                                                     \
      short8 G = bfrag_lds(RDP, biasF, (u), h, src0, src1, lo2,           \
                           n0, n1, n2, n3);                               \
      A0 = mfma16(*(const short8*)&W2[((u) * 8 + 0) * 512], G, A0);       \
      A1 = mfma16(*(const short8*)&W2[((u) * 8 + 1) * 512], G, A1);       \
      A2 = mfma16(*(const short8*)&W2[((u) * 8 + 2) * 512], G, A2);       \
      A3 = mfma16(*(const short8*)&W2[((u) * 8 + 3) * 512], G, A3);       \
      A4 = mfma16(*(const short8*)&W2[((u) * 8 + 4) * 512], G, A4);       \
      A5 = mfma16(*(const short8*)&W2[((u) * 8 + 5) * 512], G, A5);       \
      A6 = mfma16(*(const short8*)&W2[((u) * 8 + 6) * 512], G, A6);       \
      A7 = mfma16(*(const short8*)&W2[((u) * 8 + 7) * 512], G, A7);       \
    }
    stageE2(pk, P2, 1, w, l);                       // slices 2,3 -> P2
    E_SLICE(0, wbl0)
    E_SLICE(1, wbl1)
    __syncthreads();
    stageE2(pk, WA, 2, w, l);                       // slices 4,5 -> WA
    E_SLICE(2, pbl0)
    E_SLICE(3, pbl1)
    __syncthreads();
    stageE2(pk, P2, 3, w, l);                       // slices 6,7 -> P2
    E_SLICE(4, wbl0)
    E_SLICE(5, wbl1)
    __syncthreads();
    E_SLICE(6, pbl0)
    E_SLICE(7, pbl1)
    __syncthreads();   // syncE: all P2-staged reads done
#undef E_SLICE
#define E_EPI(t2, A)                                                      \
    {                                                                     \
      float4 b4 = *(const float4*)&f_b2[16 * (t2) + 4 * h];               \
      u32x2 dd;                                                           \
      dd[0] = pkbf(A[0] + b4.x, A[1] + b4.y);                             \
      dd[1] = pkbf(A[2] + b4.z, A[3] + b4.w);                             \
      *(u32x2*)&P2[(16 * w + c) * LB + 16 * (t2) + 4 * h] = dd;           \
    }
    E_EPI(0, A0) E_EPI(1, A1) E_EPI(2, A2) E_EPI(3, A3)
    E_EPI(4, A4) E_EPI(5, A5) E_EPI(6, A6) E_EPI(7, A7)
#undef E_EPI
  }
  __syncthreads();   // sync4: upd complete

  float4* og = (float4*)(out + base);
  STORE_F(0, xp0)
  STORE_F(1, xp1)
  STORE_F(2, xp2)
  STORE_F(3, xp3)
}

extern "C" void kernel_launch(void* const* d_in, const int* in_sizes, int n_in,
                              void* d_out, int out_size, void* d_ws, size_t ws_size,
                              hipStream_t stream) {
  (void)in_sizes; (void)n_in; (void)out_size; (void)ws_size;
  const float* x    = (const float*)d_in[0];
  const float* ln_g = (const float*)d_in[1];
  const float* ln_b = (const float*)d_in[2];
  const float* cW1  = (const float*)d_in[3];
  const float* c_b1 = (const float*)d_in[4];
  const float* cW2  = (const float*)d_in[5];
  const float* c_b2 = (const float*)d_in[6];
  const float* dW1  = (const float*)d_in[7];
  const float* d_b1 = (const float*)d_in[8];
  const float* dW2  = (const float*)d_in[9];
  const float* d_b2 = (const float*)d_in[10];
  const float* fW1  = (const float*)d_in[11];
  const float* f_b1 = (const float*)d_in[12];
  const float* fW2  = (const float*)d_in[13];
  const float* f_b2 = (const float*)d_in[14];
  short* pk   = (short*)d_ws;                         // 256 KB fragments
  float* bfv  = (float*)((char*)d_ws + BF_OFF);       // 512 folded-bias floats
  float* out  = (float*)d_out;

  pack_weights_k<<<64, 256, 0, stream>>>(cW1, cW2, dW1, dW2, fW1, fW2, ln_g, pk);
  bias_fold_k<<<2, 256, 0, stream>>>(ln_b, cW1, c_b1, d_b1, fW1, f_b1, bfv);
  hemi_fused_k<<<8192, 256, 0, stream>>>(x, pk, bfv, c_b2, d_b2, f_b2, out);
}